// Round 2
// baseline (270.138 us; speedup 1.0000x reference)
//
#include <hip/hip_runtime.h>
#include <hip/hip_bf16.h>

// Embedding gather: out[b,s,:] = W[x[b,s],:]
//   x: (4, 4096) int32      -> 16384 rows
//   W: (50257, 1024) float32
//   out: (4, 4096, 1024) float32
//
// Each row is 1024 f32 = 256 float4. One 256-thread block per row:
// thread t copies float4 #t of the row. Fully coalesced 16B/lane.

static constexpr int D_MODEL_VEC4 = 256;  // 1024 floats / 4

__global__ __launch_bounds__(256) void embed_gather_kernel(
    const int* __restrict__ x,
    const float4* __restrict__ W,
    float4* __restrict__ out,
    int n_rows) {
    for (int row = blockIdx.x; row < n_rows; row += gridDim.x) {
        const int idx = x[row];
        const float4* __restrict__ src = W + (size_t)idx * D_MODEL_VEC4;
        float4* __restrict__ dst = out + (size_t)row * D_MODEL_VEC4;
        dst[threadIdx.x] = src[threadIdx.x];
    }
}

extern "C" void kernel_launch(void* const* d_in, const int* in_sizes, int n_in,
                              void* d_out, int out_size, void* d_ws, size_t ws_size,
                              hipStream_t stream) {
    const int* x = (const int*)d_in[0];          // (B*S,) int32 indices
    const float4* W = (const float4*)d_in[1];    // (VOCAB, 1024) f32, viewed as float4
    float4* out = (float4*)d_out;                // (B*S, 1024) f32, viewed as float4

    const int n_rows = in_sizes[0];              // B*S = 16384

    const int block = 256;
    int grid = n_rows;                           // one block per row
    if (grid > 16384) grid = 16384;

    embed_gather_kernel<<<grid, block, 0, stream>>>(x, W, out, n_rows);
}